// Round 1
// baseline (658.681 us; speedup 1.0000x reference)
//
#include <hip/hip_runtime.h>
#include <stdint.h>

// BitInput: bit-exact jax.random.uniform(key(42), [1024,512,256]) via
// partitionable Threefry-2x32 (absmax=0 verified), thresholded by
// p = inp[flat>>8].
//
//   bits[i] = o0 ^ o1, (o0,o1) = threefry2x32((0,42), (0,i))
//   out[i]  = ((bits[i] >> 9) < ceil(p * 2^23)) ? 1.0f : 0.0f
//
// Round-6: same math as round-5, restructured into 3 strict phases:
//   phase 1: ALL 4 input loads + thr conversion (no stores in flight ->
//            the s_waitcnt before thr use drains only cheap L1/L2 loads)
//   phase 2: all 16 Threefry chains (pure VALU)
//   phase 3: all 4 nontemporal stores, fire-and-forget (nothing ever
//            waits on them -> no vmcnt drain of ~800-cycle NT HBM stores)
// Theory: round-5 interleaved per-q loads after NT stores; the waitcnt for
// each thr load then drained the store queue (vmcnt counts stores too),
// stalling ~half the kernel's cycles.

typedef float vfloat4 __attribute__((ext_vector_type(4)));

__device__ __forceinline__ uint32_t rotl(uint32_t x, uint32_t r) {
    return __builtin_amdgcn_alignbit(x, x, 32u - r);   // rotr(32-r) = rotl(r)
}

// Two independent Threefry-2x32((0,42)) chains, interleaved statement-by-
// statement so the instruction stream carries ILP=2 regardless of scheduling.
__device__ __forceinline__ void tf_bits2(uint32_t ia, uint32_t ib,
                                         uint32_t& ra, uint32_t& rb) {
    const uint32_t k1 = 42u;
    const uint32_t k2 = 0x1BD11BDAu ^ k1;   // 0x1BD11BF0
    uint32_t a0 = 0u,  a1 = ia + k1;
    uint32_t b0 = 0u,  b1 = ib + k1;
#define RND2(r) \
    a0 += a1; b0 += b1; \
    a1 = rotl(a1,(r)); b1 = rotl(b1,(r)); \
    a1 ^= a0; b1 ^= b0;
#define INJ2(ca,cb) \
    a0 += (ca); b0 += (ca); a1 += (cb); b1 += (cb);
    RND2(13u) RND2(15u) RND2(26u) RND2( 6u)  INJ2(k1,      k2 + 1u)
    RND2(17u) RND2(29u) RND2(16u) RND2(24u)  INJ2(k2,      0u + 2u)
    RND2(13u) RND2(15u) RND2(26u) RND2( 6u)  INJ2(0u,      k1 + 3u)
    RND2(17u) RND2(29u) RND2(16u) RND2(24u)  INJ2(k1,      k2 + 4u)
    RND2(13u) RND2(15u) RND2(26u) RND2( 6u)  INJ2(k2,      0u + 5u)
#undef RND2
#undef INJ2
    ra = a0 ^ a1;
    rb = b0 ^ b1;
}

__device__ __forceinline__ vfloat4 gen4(uint32_t base, uint32_t thr) {
    uint32_t m0, m1, m2, m3;
    tf_bits2(base + 0u, base + 1u, m0, m1);
    tf_bits2(base + 2u, base + 3u, m2, m3);
    vfloat4 r;
    r.x = ((m0 >> 9) < thr) ? 1.0f : 0.0f;
    r.y = ((m1 >> 9) < thr) ? 1.0f : 0.0f;
    r.z = ((m2 >> 9) < thr) ? 1.0f : 0.0f;
    r.w = ((m3 >> 9) < thr) ? 1.0f : 0.0f;
    return r;
}

__global__ __launch_bounds__(256) void bitinput_kernel(
        const float* __restrict__ inp, float* __restrict__ out,
        uint32_t quarter_n) {
    uint32_t t  = blockIdx.x * blockDim.x + threadIdx.x;
    uint32_t i0 = t * 4u;
    if (i0 >= quarter_n) return;

    // ---- Phase 1: ALL input loads up front (no stores in flight) ----
    // (i0 + q*quarter_n) >> 8 == (i0>>8) + q*(quarter_n>>8): quarter_n's
    // low 8 bits are zero, so no carry interaction.
    uint32_t pidx  = i0 >> 8;
    uint32_t pstep = quarter_n >> 8;
    float p0 = inp[pidx];
    float p1 = inp[pidx +      pstep];
    float p2 = inp[pidx + 2u * pstep];
    float p3 = inp[pidx + 3u * pstep];
    uint32_t thr0 = (uint32_t)ceilf(p0 * 8388608.0f);
    uint32_t thr1 = (uint32_t)ceilf(p1 * 8388608.0f);
    uint32_t thr2 = (uint32_t)ceilf(p2 * 8388608.0f);
    uint32_t thr3 = (uint32_t)ceilf(p3 * 8388608.0f);

    // ---- Phase 2: 16 Threefry chains, pure VALU ----
    vfloat4 r0 = gen4(i0,                  thr0);
    vfloat4 r1 = gen4(i0 +      quarter_n, thr1);
    vfloat4 r2 = gen4(i0 + 2u * quarter_n, thr2);
    vfloat4 r3 = gen4(i0 + 3u * quarter_n, thr3);

    // ---- Phase 3: stores last, fire-and-forget ----
    // perfectly coalesced 16 B/lane; nontemporal: out is write-once
    vfloat4* o   = reinterpret_cast<vfloat4*>(out) + t;
    uint32_t vst = quarter_n >> 2;   // vfloat4 stride between q-streams
    __builtin_nontemporal_store(r0, o);
    __builtin_nontemporal_store(r1, o +      vst);
    __builtin_nontemporal_store(r2, o + 2u * vst);
    __builtin_nontemporal_store(r3, o + 3u * vst);
}

extern "C" void kernel_launch(void* const* d_in, const int* in_sizes, int n_in,
                              void* d_out, int out_size, void* d_ws, size_t ws_size,
                              hipStream_t stream) {
    const float* inp = (const float*)d_in[0];
    float* out = (float*)d_out;

    uint32_t n = (uint32_t)out_size;          // 2^27
    uint32_t quarter_n = n >> 2;              // 2^25
    uint32_t threads_needed = quarter_n >> 2; // 16 outputs per thread
    dim3 block(256);
    dim3 grid((threads_needed + block.x - 1) / block.x);
    bitinput_kernel<<<grid, block, 0, stream>>>(inp, out, quarter_n);
}

// Round 2
// 655.658 us; speedup vs baseline: 1.0046x; 1.0046x over previous
//
#include <hip/hip_runtime.h>
#include <stdint.h>

// BitInput: bit-exact jax.random.uniform(key(42), [1024,512,256]) via
// partitionable Threefry-2x32 (absmax=0 verified), thresholded by
// p = inp[flat>>8].
//
//   bits[i] = o0 ^ o1, (o0,o1) = threefry2x32((0,42), (0,i))
//   out[i]  = ((bits[i] >> 9) < ceil(p * 2^23)) ? 1.0f : 0.0f
//
// Round-7: round-6 structure, NONTEMPORAL HINT REMOVED (plain cached
// stores). Theory: rounds 4-6 all land at kernel~312us = 512MiB/1.72TB/s
// regardless of schedule, while the harness's own fillBuffer hits
// 6.25TB/s on the same memory -- suspect the nt store path (L2 bypass)
// caps streaming write BW. Plain dwordx4 stores stream through L2 like
// the fill does. Predict kernel ~312 -> ~160us (VALU-issue-bound),
// dur_us ~658 -> ~500.

typedef float vfloat4 __attribute__((ext_vector_type(4)));

__device__ __forceinline__ uint32_t rotl(uint32_t x, uint32_t r) {
    return __builtin_amdgcn_alignbit(x, x, 32u - r);   // rotr(32-r) = rotl(r)
}

// Two independent Threefry-2x32((0,42)) chains, interleaved statement-by-
// statement so the instruction stream carries ILP=2 regardless of scheduling.
__device__ __forceinline__ void tf_bits2(uint32_t ia, uint32_t ib,
                                         uint32_t& ra, uint32_t& rb) {
    const uint32_t k1 = 42u;
    const uint32_t k2 = 0x1BD11BDAu ^ k1;   // 0x1BD11BF0
    uint32_t a0 = 0u,  a1 = ia + k1;
    uint32_t b0 = 0u,  b1 = ib + k1;
#define RND2(r) \
    a0 += a1; b0 += b1; \
    a1 = rotl(a1,(r)); b1 = rotl(b1,(r)); \
    a1 ^= a0; b1 ^= b0;
#define INJ2(ca,cb) \
    a0 += (ca); b0 += (ca); a1 += (cb); b1 += (cb);
    RND2(13u) RND2(15u) RND2(26u) RND2( 6u)  INJ2(k1,      k2 + 1u)
    RND2(17u) RND2(29u) RND2(16u) RND2(24u)  INJ2(k2,      0u + 2u)
    RND2(13u) RND2(15u) RND2(26u) RND2( 6u)  INJ2(0u,      k1 + 3u)
    RND2(17u) RND2(29u) RND2(16u) RND2(24u)  INJ2(k1,      k2 + 4u)
    RND2(13u) RND2(15u) RND2(26u) RND2( 6u)  INJ2(k2,      0u + 5u)
#undef RND2
#undef INJ2
    ra = a0 ^ a1;
    rb = b0 ^ b1;
}

__device__ __forceinline__ vfloat4 gen4(uint32_t base, uint32_t thr) {
    uint32_t m0, m1, m2, m3;
    tf_bits2(base + 0u, base + 1u, m0, m1);
    tf_bits2(base + 2u, base + 3u, m2, m3);
    vfloat4 r;
    r.x = ((m0 >> 9) < thr) ? 1.0f : 0.0f;
    r.y = ((m1 >> 9) < thr) ? 1.0f : 0.0f;
    r.z = ((m2 >> 9) < thr) ? 1.0f : 0.0f;
    r.w = ((m3 >> 9) < thr) ? 1.0f : 0.0f;
    return r;
}

__global__ __launch_bounds__(256) void bitinput_kernel(
        const float* __restrict__ inp, float* __restrict__ out,
        uint32_t quarter_n) {
    uint32_t t  = blockIdx.x * blockDim.x + threadIdx.x;
    uint32_t i0 = t * 4u;
    if (i0 >= quarter_n) return;

    // ---- Phase 1: ALL input loads up front ----
    // (i0 + q*quarter_n) >> 8 == (i0>>8) + q*(quarter_n>>8): quarter_n's
    // low 8 bits are zero, so no carry interaction.
    uint32_t pidx  = i0 >> 8;
    uint32_t pstep = quarter_n >> 8;
    float p0 = inp[pidx];
    float p1 = inp[pidx +      pstep];
    float p2 = inp[pidx + 2u * pstep];
    float p3 = inp[pidx + 3u * pstep];
    uint32_t thr0 = (uint32_t)ceilf(p0 * 8388608.0f);
    uint32_t thr1 = (uint32_t)ceilf(p1 * 8388608.0f);
    uint32_t thr2 = (uint32_t)ceilf(p2 * 8388608.0f);
    uint32_t thr3 = (uint32_t)ceilf(p3 * 8388608.0f);

    // ---- Phase 2: 16 Threefry chains, pure VALU ----
    vfloat4 r0 = gen4(i0,                  thr0);
    vfloat4 r1 = gen4(i0 +      quarter_n, thr1);
    vfloat4 r2 = gen4(i0 + 2u * quarter_n, thr2);
    vfloat4 r3 = gen4(i0 + 3u * quarter_n, thr3);

    // ---- Phase 3: stores last ----
    // perfectly coalesced 16 B/lane, PLAIN cached stores (stream via L2
    // like the 6.25 TB/s fillBuffer does; nt hint removed this round)
    vfloat4* o   = reinterpret_cast<vfloat4*>(out) + t;
    uint32_t vst = quarter_n >> 2;   // vfloat4 stride between q-streams
    o[0]        = r0;
    o[vst]      = r1;
    o[2u * vst] = r2;
    o[3u * vst] = r3;
}

extern "C" void kernel_launch(void* const* d_in, const int* in_sizes, int n_in,
                              void* d_out, int out_size, void* d_ws, size_t ws_size,
                              hipStream_t stream) {
    const float* inp = (const float*)d_in[0];
    float* out = (float*)d_out;

    uint32_t n = (uint32_t)out_size;          // 2^27
    uint32_t quarter_n = n >> 2;              // 2^25
    uint32_t threads_needed = quarter_n >> 2; // 16 outputs per thread
    dim3 block(256);
    dim3 grid((threads_needed + block.x - 1) / block.x);
    bitinput_kernel<<<grid, block, 0, stream>>>(inp, out, quarter_n);
}

// Round 4
// 652.360 us; speedup vs baseline: 1.0097x; 1.0051x over previous
//
#include <hip/hip_runtime.h>
#include <stdint.h>

// BitInput: bit-exact jax.random.uniform(key(42), [1024,512,256]) via
// partitionable Threefry-2x32 (absmax=0 verified), thresholded by
// p = inp[flat>>8].
//
//   bits[i] = o0 ^ o1, (o0,o1) = threefry2x32((0,42), (0,i))
//   out[i]  = ((bits[i] >> 9) < ceil(p * 2^23)) ? 1.0f : 0.0f
//
// Round-9 = round-8 resubmitted (round-8 hit an infra failure: container
// acquisition failed twice; no kernel result). Occupancy probe:
// rounds 5/6/7 ({loop,3-phase} x {nt,cached}) all land 652-659us ->
// schedule-insensitive. Remaining theory: VALU issue-rate wall, possibly
// aggravated by VGPR pressure (3-phase holds up to 16 chains + 16
// results live). This round: minimal-live-state per-q loop (4 chains at
// a time) + __launch_bounds__(256, 8) to force VGPR <= 64 -> 8
// waves/SIMD. Math and thread->index mapping identical to verified
// rounds. Predict: if occupancy-limited, ~610-630us; if unchanged, the
// kernel is at the sustained-issue wall (roofline: fill ~343 + threefry
// ~160-195 issue-bound + dispatch overhead).

typedef float vfloat4 __attribute__((ext_vector_type(4)));

__device__ __forceinline__ uint32_t rotl(uint32_t x, uint32_t r) {
    return __builtin_amdgcn_alignbit(x, x, 32u - r);   // rotr(32-r) = rotl(r)
}

// Two independent Threefry-2x32((0,42)) chains, interleaved statement-by-
// statement so the instruction stream carries ILP=2 regardless of scheduling.
__device__ __forceinline__ void tf_bits2(uint32_t ia, uint32_t ib,
                                         uint32_t& ra, uint32_t& rb) {
    const uint32_t k1 = 42u;
    const uint32_t k2 = 0x1BD11BDAu ^ k1;   // 0x1BD11BF0
    uint32_t a0 = 0u,  a1 = ia + k1;
    uint32_t b0 = 0u,  b1 = ib + k1;
#define RND2(r) \
    a0 += a1; b0 += b1; \
    a1 = rotl(a1,(r)); b1 = rotl(b1,(r)); \
    a1 ^= a0; b1 ^= b0;
#define INJ2(ca,cb) \
    a0 += (ca); b0 += (ca); a1 += (cb); b1 += (cb);
    RND2(13u) RND2(15u) RND2(26u) RND2( 6u)  INJ2(k1,      k2 + 1u)
    RND2(17u) RND2(29u) RND2(16u) RND2(24u)  INJ2(k2,      0u + 2u)
    RND2(13u) RND2(15u) RND2(26u) RND2( 6u)  INJ2(0u,      k1 + 3u)
    RND2(17u) RND2(29u) RND2(16u) RND2(24u)  INJ2(k1,      k2 + 4u)
    RND2(13u) RND2(15u) RND2(26u) RND2( 6u)  INJ2(k2,      0u + 5u)
#undef RND2
#undef INJ2
    ra = a0 ^ a1;
    rb = b0 ^ b1;
}

__global__ __launch_bounds__(256, 8) void bitinput_kernel(
        const float* __restrict__ inp, float* __restrict__ out,
        uint32_t quarter_n) {
    uint32_t t  = blockIdx.x * blockDim.x + threadIdx.x;
    uint32_t i0 = t * 4u;
    if (i0 >= quarter_n) return;

#pragma unroll
    for (int q = 0; q < 4; ++q) {
        uint32_t base = i0 + (uint32_t)q * quarter_n;
        // 4 | 256 and base % 4 == 0: one probability per group of 4.
        // pidx = base>>8 is wave-uniform (t>>6): broadcast L1-hit load.
        uint32_t thr = (uint32_t)ceilf(inp[base >> 8] * 8388608.0f);

        uint32_t m0, m1, m2, m3;
        tf_bits2(base + 0u, base + 1u, m0, m1);
        tf_bits2(base + 2u, base + 3u, m2, m3);

        vfloat4 r;
        r.x = ((m0 >> 9) < thr) ? 1.0f : 0.0f;
        r.y = ((m1 >> 9) < thr) ? 1.0f : 0.0f;
        r.z = ((m2 >> 9) < thr) ? 1.0f : 0.0f;
        r.w = ((m3 >> 9) < thr) ? 1.0f : 0.0f;

        // perfectly coalesced 16 B/lane
        *(reinterpret_cast<vfloat4*>(out + base - i0) + t) = r;
    }
}

extern "C" void kernel_launch(void* const* d_in, const int* in_sizes, int n_in,
                              void* d_out, int out_size, void* d_ws, size_t ws_size,
                              hipStream_t stream) {
    const float* inp = (const float*)d_in[0];
    float* out = (float*)d_out;

    uint32_t n = (uint32_t)out_size;          // 2^27
    uint32_t quarter_n = n >> 2;              // 2^25
    uint32_t threads_needed = quarter_n >> 2; // 16 outputs per thread
    dim3 block(256);
    dim3 grid((threads_needed + block.x - 1) / block.x);
    bitinput_kernel<<<grid, block, 0, stream>>>(inp, out, quarter_n);
}

// Round 5
// 650.793 us; speedup vs baseline: 1.0121x; 1.0024x over previous
//
#include <hip/hip_runtime.h>
#include <stdint.h>

// BitInput: bit-exact jax.random.uniform(key(42), [1024,512,256]) via
// partitionable Threefry-2x32 (absmax=0 verified), thresholded by
// p = inp[flat>>8].
//
//   bits[i] = o0 ^ o1, (o0,o1) = threefry2x32((0,42), (0,i))
//   out[i]  = ((bits[i] >> 9) < ceil(p * 2^23)) ? 1.0f : 0.0f
//
// Round-10: last source-level lever = static instruction count.
// Null matrix so far (all 652-659us): schedule shape x3, NT vs cached
// stores, load hoisting, occupancy cap (lb(256,8)).
// This round:
//  (a) force v_add3_u32 at the 4 key-injection boundaries: the original
//      "x0 += ks; ...; x0 += x1" pair of serial adds is rewritten as
//      x0 = x0 + ks + x1 (one VOP3 add3, ks lives in SGPR). Exact same
//      arithmetic mod 2^32. 3 real fusions/chain x 16 chains = 48
//      instrs/thread (~4% of kernel) IF the compiler wasn't already
//      fusing.
//  (b) wave-uniform p index via readfirstlane -> s_load_dword scalar
//      path (i0>>8 == t>>6, identical across the wave): removes 4
//      per-lane VMEM loads + their waits.
// Predict: ~638us if the fusion is new; >=648 => instruction floor
// confirmed, declare roofline (fill 343us at write-roofline + kernel
// ~309us at sustained-issue/clock wall, every source lever null).

typedef float vfloat4 __attribute__((ext_vector_type(4)));

__device__ __forceinline__ uint32_t rotl(uint32_t x, uint32_t r) {
    return __builtin_amdgcn_alignbit(x, x, 32u - r);   // rotr(32-r) = rotl(r)
}

// Two independent Threefry-2x32((0,42)) chains, interleaved statement-by-
// statement. Key-injection boundaries fused into the following round's
// x0-add as a 3-input add (v_add3_u32):
//   orig: x0 += ca;         x1 += cb;  x0 += x1;  x1 = rotl(x1,r)^x0
//   new : x1 += cb;  x0 = x0 + ca + x1;           x1 = rotl(x1,r)^x0
// (identical mod-2^32 arithmetic, one add fewer per boundary per chain)
__device__ __forceinline__ void tf_bits2(uint32_t ia, uint32_t ib,
                                         uint32_t& ra, uint32_t& rb) {
    const uint32_t k1 = 42u;
    const uint32_t k2 = 0x1BD11BDAu ^ k1;   // 0x1BD11BF0
    uint32_t a0 = 0u,  a1 = ia + k1;
    uint32_t b0 = 0u,  b1 = ib + k1;
#define RND2(r) \
    a0 += a1; b0 += b1; \
    a1 = rotl(a1,(r)); b1 = rotl(b1,(r)); \
    a1 ^= a0; b1 ^= b0;
#define IRND2(ca,cb,r) \
    a1 += (cb); b1 += (cb); \
    a0 = a0 + (ca) + a1; b0 = b0 + (ca) + b1; \
    a1 = rotl(a1,(r)); b1 = rotl(b1,(r)); \
    a1 ^= a0; b1 ^= b0;
    /* rounds 1-4 */
    RND2(13u) RND2(15u) RND2(26u) RND2( 6u)
    /* inj1 + rounds 5-8 */
    IRND2(k1, k2 + 1u, 17u) RND2(29u) RND2(16u) RND2(24u)
    /* inj2 + rounds 9-12 */
    IRND2(k2, 0u + 2u, 13u) RND2(15u) RND2(26u) RND2( 6u)
    /* inj3 + rounds 13-16 */
    IRND2(0u, k1 + 3u, 17u) RND2(29u) RND2(16u) RND2(24u)
    /* inj4 + rounds 17-20 */
    IRND2(k1, k2 + 4u, 13u) RND2(15u) RND2(26u) RND2( 6u)
#undef RND2
#undef IRND2
    /* final injection (no following round -> plain adds) */
    a0 += k2; b0 += k2;
    a1 += 5u; b1 += 5u;
    ra = a0 ^ a1;
    rb = b0 ^ b1;
}

__global__ __launch_bounds__(256, 8) void bitinput_kernel(
        const float* __restrict__ inp, float* __restrict__ out,
        uint32_t quarter_n) {
    uint32_t t  = blockIdx.x * blockDim.x + threadIdx.x;
    uint32_t i0 = t * 4u;
    if (i0 >= quarter_n) return;

    // i0>>8 == t>>6: identical for all 64 lanes of the wave (grid is
    // exact, all lanes active). readfirstlane pins it in an SGPR so the
    // four p loads go down the scalar (s_load_dword) path.
    uint32_t pidx  = __builtin_amdgcn_readfirstlane(i0 >> 8);
    uint32_t pstep = quarter_n >> 8;

#pragma unroll
    for (int q = 0; q < 4; ++q) {
        uint32_t base = i0 + (uint32_t)q * quarter_n;
        // 4 | 256 and base % 4 == 0: one probability per group of 4.
        uint32_t thr = (uint32_t)ceilf(inp[pidx + (uint32_t)q * pstep]
                                       * 8388608.0f);

        uint32_t m0, m1, m2, m3;
        tf_bits2(base + 0u, base + 1u, m0, m1);
        tf_bits2(base + 2u, base + 3u, m2, m3);

        vfloat4 r;
        r.x = ((m0 >> 9) < thr) ? 1.0f : 0.0f;
        r.y = ((m1 >> 9) < thr) ? 1.0f : 0.0f;
        r.z = ((m2 >> 9) < thr) ? 1.0f : 0.0f;
        r.w = ((m3 >> 9) < thr) ? 1.0f : 0.0f;

        // perfectly coalesced 16 B/lane
        *(reinterpret_cast<vfloat4*>(out + base - i0) + t) = r;
    }
}

extern "C" void kernel_launch(void* const* d_in, const int* in_sizes, int n_in,
                              void* d_out, int out_size, void* d_ws, size_t ws_size,
                              hipStream_t stream) {
    const float* inp = (const float*)d_in[0];
    float* out = (float*)d_out;

    uint32_t n = (uint32_t)out_size;          // 2^27
    uint32_t quarter_n = n >> 2;              // 2^25
    uint32_t threads_needed = quarter_n >> 2; // 16 outputs per thread
    dim3 block(256);
    dim3 grid((threads_needed + block.x - 1) / block.x);
    bitinput_kernel<<<grid, block, 0, stream>>>(inp, out, quarter_n);
}